// Round 3
// baseline (421.759 us; speedup 1.0000x reference)
//
#include <hip/hip_runtime.h>

typedef float  floatx4  __attribute__((ext_vector_type(4)));
typedef short  bf16x8   __attribute__((ext_vector_type(8)));
typedef float  facc4    __attribute__((ext_vector_type(4)));

__device__ __forceinline__ unsigned short f2bf(float f) {
  unsigned u = __builtin_bit_cast(unsigned, f);
  u = u + 0x7fffu + ((u >> 16) & 1u);   // round-to-nearest-even
  return (unsigned short)(u >> 16);
}

// chunk boundaries on i, balancing ~903 rotations/chunk (9 chunks)
__device__ const int kBounds[10] = {0, 7, 15, 23, 32, 42, 54, 67, 85, 127};

// ---------------- K1: chunk partial products, w-row in LDS ----------------
// Thread r owns row r of the chunk product in LDS (dynamic index OK, no spill).
// Rotation (i,j): wi' = wi*c + wj*s ; wj' = wj*c - wi*s  (column ops -> rows independent)
__global__ __launch_bounds__(128) void k_wgen(const float* __restrict__ ang,
                                              float* __restrict__ out) {
  __shared__ float  lw[128 * 129];  // [row][col], pad 129 -> bank = (row+col)%32, free
  __shared__ float2 lcs[960];       // max chunk = 932 rotations
  const int tid = threadIdx.x;
  const int I0 = kBounds[blockIdx.x], I1 = kBounds[blockIdx.x + 1];
  const int P0 = I0 * 127 - (I0 * (I0 - 1)) / 2;
  const int P1 = I1 * 127 - (I1 * (I1 - 1)) / 2;
  const int nrot = P1 - P0;

  for (int p = tid; p < nrot; p += 128) {
    float s, c;
    sincosf(ang[P0 + p], &s, &c);
    lcs[p].x = c;
    lcs[p].y = s;
  }
  float* wr = lw + tid * 129;   // this thread's row — private, no sync needed
  for (int c = 0; c < 128; ++c) wr[c] = 0.0f;
  wr[tid] = 1.0f;
  __syncthreads();              // lcs ready

  int p = 0;
  for (int i = I0; i < I1; ++i) {
    float wi = wr[i];
    for (int j = i + 1; j < 128; ++j, ++p) {
      const float2 cs2 = lcs[p];       // ds_read_b64 broadcast
      const float wj = wr[j];
      wr[j] = fmaf(wj, cs2.x, -(wi * cs2.y));
      wi    = fmaf(wj, cs2.y, wi * cs2.x);
    }
    wr[i] = wi;
  }
  __syncthreads();              // writeout reads other threads' rows
  float* dst = out + (size_t)blockIdx.x * 16384;
  for (int e = tid; e < 16384; e += 128) {
    dst[e] = lw[(e >> 7) * 129 + (e & 127)];  // coalesced global, conflict-free LDS
  }
}

// ---------------- K2: combine W = C0*C1*...*C8, emit Wt bf16 [n][128] ----------------
__global__ __launch_bounds__(128) void k_combine(const float* __restrict__ chunks,
                                                 unsigned short* __restrict__ wt) {
  __shared__ float sv[128];
  const int r = blockIdx.x;   // row of W (k index of GEMM)
  const int t = threadIdx.x;  // column of W (feature index)
  float v = chunks[r * 128 + t];  // row r of C0
  for (int m = 1; m < 9; ++m) {
    __syncthreads();
    sv[t] = v;
    __syncthreads();
    const float* Cm = chunks + m * 16384 + t;
    float a0 = 0.f, a1 = 0.f, a2 = 0.f, a3 = 0.f;  // ILP-4
#pragma unroll
    for (int k = 0; k < 128; k += 4) {
      a0 = fmaf(sv[k],     Cm[(k)     * 128], a0);
      a1 = fmaf(sv[k + 1], Cm[(k + 1) * 128], a1);
      a2 = fmaf(sv[k + 2], Cm[(k + 2) * 128], a2);
      a3 = fmaf(sv[k + 3], Cm[(k + 3) * 128], a3);
    }
    v = (a0 + a1) + (a2 + a3);
  }
  wt[t * 128 + r] = f2bf(v);  // Wt[feature][k], unpadded (swizzled at GEMM staging)
}

// ---------------- K3: y = x @ W + bias  (bf16 MFMA, fp32 acc) ----------------
// A = Wt (features on M), B = x (batch on N). sW XOR-swizzled: 16B chunk ch of row
// stored at ch ^ (row & 15) -> b128 reads hit all 32 banks evenly.
__global__ __launch_bounds__(256, 4) void k_gemm(const float* __restrict__ x,
                                                 const unsigned short* __restrict__ wt,
                                                 const float* __restrict__ bias,
                                                 float* __restrict__ y) {
  __shared__ unsigned short sW[128 * 128];  // 32768 B
  __shared__ float sB[128];
  const int tid = threadIdx.x;
  {
    const floatx4* src = (const floatx4*)wt;
    floatx4* dst = (floatx4*)sW;
#pragma unroll
    for (int i2 = 0; i2 < 8; ++i2) {
      const int idx = tid + i2 * 256;           // 2048 16B chunks
      const int row = idx >> 4, ch = idx & 15;
      dst[(row << 4) | (ch ^ (row & 15))] = src[idx];
    }
    if (tid < 128) sB[tid] = bias[tid];
  }
  __syncthreads();

  const int wave = tid >> 6, lane = tid & 63;
  const int m16 = lane & 15, h = lane >> 4;

  const size_t row0 = (size_t)blockIdx.x * 256 + wave * 64 + m16;
  const float* xw = x + row0 * 128 + h * 8;
  float* yw = y + row0 * 128;

  floatx4 a[2][8];
#pragma unroll
  for (int c = 0; c < 4; ++c) {   // prologue: iterations 0 and 1
    a[0][2 * c]     = *(const floatx4*)(xw + c * 32);
    a[0][2 * c + 1] = *(const floatx4*)(xw + c * 32 + 4);
  }
#pragma unroll
  for (int c = 0; c < 4; ++c) {
    a[1][2 * c]     = *(const floatx4*)(xw + 2048 + c * 32);
    a[1][2 * c + 1] = *(const floatx4*)(xw + 2048 + c * 32 + 4);
  }

#pragma unroll
  for (int it = 0; it < 4; ++it) {
    const int cur = it & 1;
    bf16x8 af[4];
#pragma unroll
    for (int c = 0; c < 4; ++c) {
#pragma unroll
      for (int q = 0; q < 8; ++q) {
        const float f = (q < 4) ? a[cur][2 * c][q] : a[cur][2 * c + 1][q - 4];
        af[c][q] = (short)f2bf(f);
      }
    }
    if (it < 2) {  // depth-2 prefetch into the buffer just consumed
      const float* xp = xw + (size_t)(it + 2) * 2048;
#pragma unroll
      for (int c = 0; c < 4; ++c) {
        a[cur][2 * c]     = *(const floatx4*)(xp + c * 32);
        a[cur][2 * c + 1] = *(const floatx4*)(xp + c * 32 + 4);
      }
    }
    facc4 acc[8];
#pragma unroll
    for (int t = 0; t < 8; ++t) acc[t] = *(const facc4*)(sB + t * 16 + h * 4);  // bias as C
#pragma unroll
    for (int c = 0; c < 4; ++c) {
#pragma unroll
      for (int t = 0; t < 8; ++t) {
        const int row = t * 16 + m16;
        const bf16x8 bw =
            *(const bf16x8*)(sW + (((row << 4) | (((c << 2) | h) ^ m16)) << 3));
        acc[t] = __builtin_amdgcn_mfma_f32_16x16x32_bf16(bw, af[c], acc[t], 0, 0, 0);
      }
    }
    float* yr = yw + it * 2048;
#pragma unroll
    for (int t = 0; t < 8; ++t) {  // y is write-once: bypass LLC, keep x resident
      __builtin_nontemporal_store(acc[t], (floatx4*)(yr + t * 16 + h * 4));
    }
  }
}

extern "C" void kernel_launch(void* const* d_in, const int* in_sizes, int n_in,
                              void* d_out, int out_size, void* d_ws, size_t ws_size,
                              hipStream_t stream) {
  const float* x    = (const float*)d_in[0];
  const float* ang  = (const float*)d_in[1];
  const float* bias = (const float*)d_in[2];
  float* y = (float*)d_out;

  char* ws = (char*)d_ws;
  float* chunks      = (float*)ws;                      // 9 * 64 KiB = 589824 B
  unsigned short* wt = (unsigned short*)(ws + 589824);  // 32768 B

  k_wgen   <<<9,    128, 0, stream>>>(ang, chunks);
  k_combine<<<128,  128, 0, stream>>>(chunks, wt);
  k_gemm   <<<1024, 256, 0, stream>>>(x, wt, bias, y);
}